// Round 3
// baseline (917.790 us; speedup 1.0000x reference)
//
#include <hip/hip_runtime.h>

typedef unsigned short u16;
typedef unsigned int u32;

typedef __attribute__((ext_vector_type(8))) short short8;
typedef __attribute__((ext_vector_type(4))) float float4v;

__device__ __forceinline__ float bf2f(u16 u) { return __uint_as_float(((u32)u) << 16); }
__device__ __forceinline__ u16 f2bf(float f) {
    u32 x = __float_as_uint(f);
    return (u16)((x + 0x7fffu + ((x >> 16) & 1u)) >> 16);
}
__device__ __forceinline__ float sigmoidf_(float x) { return 1.0f / (1.0f + expf(-x)); }
// flag-aware input load: f32==1 -> buffer holds float, else bf16 u16
__device__ __forceinline__ float ldin(const void* p, size_t i, int f32) {
    return f32 ? ((const float*)p)[i] : bf2f(((const u16*)p)[i]);
}

#define B_ 128
#define T_ 20
#define VISN 196
#define VISD 512
#define EMB 256
#define HID 512
#define VOC 10000

// ---------------------------------------------------------------------------
// dtype detector: bf16 N(0,1)-scale data never has exponent field >= 0x90
// (|x| >= 2^17); raw f32 mantissa halves hit that ~44% of the time.
// ---------------------------------------------------------------------------
__global__ void detect_dtype(const u16* __restrict__ raw, int* __restrict__ flag) {
    __shared__ int cnt;
    if (threadIdx.x == 0) cnt = 0;
    __syncthreads();
    int c = 0;
    for (int i = threadIdx.x; i < 4096; i += 256) {
        u32 e = (raw[i] >> 7) & 0xFF;
        if (e >= 0x90) c++;
    }
    if (c) atomicAdd(&cnt, c);
    __syncthreads();
    if (threadIdx.x == 0) *flag = (cnt > 0) ? 1 : 0;
}

// canonicalize an input tensor to bf16
__global__ void conv_bf(const void* __restrict__ src, u16* __restrict__ dst, int n,
                        const int* __restrict__ flag) {
    int i = blockIdx.x * 256 + threadIdx.x;
    if (i >= n) return;
    int f32 = *flag;
    dst[i] = f32 ? f2bf(((const float*)src)[i]) : ((const u16*)src)[i];
}

// ---------------------------------------------------------------------------
// prep: fbar = mean_n features[b,n,:]; alpha = softmax_n(features·Wv)
// (h-term of the attention logit is constant over n -> softmax-invariant);
// ctx = sum_n alpha[n]*features[b,n,:].  One block per b. Flag-aware loads.
// ---------------------------------------------------------------------------
__global__ __launch_bounds__(256) void prep_kernel(const void* __restrict__ feat,
                                                   const void* __restrict__ Wv,
                                                   const int* __restrict__ flag,
                                                   u16* __restrict__ fbar_bf,
                                                   u16* __restrict__ ctx_bf) {
    __shared__ float wv[512];
    __shared__ float att[VISN];
    __shared__ float red[256];
    int b = blockIdx.x, tid = threadIdx.x;
    int f32 = *flag;
    wv[tid] = ldin(Wv, tid, f32);
    wv[tid + 256] = ldin(Wv, tid + 256, f32);
    __syncthreads();
    int w = tid >> 6, lane = tid & 63;
    // phase 1: att[n] = features[b,n,:]·Wv
    for (int n = w; n < VISN; n += 4) {
        size_t base = ((size_t)b * VISN + n) * VISD + lane * 8;
        float s = 0.f;
        #pragma unroll
        for (int j = 0; j < 8; j++) s += ldin(feat, base + j, f32) * wv[lane * 8 + j];
        #pragma unroll
        for (int off = 32; off; off >>= 1) s += __shfl_down(s, off);
        if (lane == 0) att[n] = s;
    }
    __syncthreads();
    // phase 2: softmax over 196
    float m = -1e30f;
    for (int i = tid; i < VISN; i += 256) m = fmaxf(m, att[i]);
    red[tid] = m; __syncthreads();
    for (int s = 128; s; s >>= 1) { if (tid < s) red[tid] = fmaxf(red[tid], red[tid + s]); __syncthreads(); }
    m = red[0]; __syncthreads();
    float sum = 0.f;
    for (int i = tid; i < VISN; i += 256) { float e = expf(att[i] - m); att[i] = e; sum += e; }
    red[tid] = sum; __syncthreads();
    for (int s = 128; s; s >>= 1) { if (tid < s) red[tid] += red[tid + s]; __syncthreads(); }
    float inv = 1.0f / red[0]; __syncthreads();
    for (int i = tid; i < VISN; i += 256) att[i] *= inv;
    __syncthreads();
    // phase 3: fbar & ctx
    #pragma unroll
    for (int half = 0; half < 2; half++) {
        int v = tid + half * 256;
        float accf = 0.f, accc = 0.f;
        size_t fbase = (size_t)b * VISN * VISD + v;
        for (int n = 0; n < VISN; n++) {
            float f = ldin(feat, fbase + (size_t)n * VISD, f32);
            accf += f;
            accc += att[n] * f;
        }
        fbar_bf[b * VISD + v] = f2bf(accf / (float)VISN);
        ctx_bf[b * VISD + v] = f2bf(accc);
    }
}

// gather embeddings, time-major rows r = t*B + b (flag-aware table read)
__global__ void gather_emb(const int* __restrict__ captions, const void* __restrict__ table,
                           const int* __restrict__ flag, u16* __restrict__ Ebf) {
    int r = blockIdx.x;
    int t = r >> 7, b = r & 127;
    int idx = captions[b * T_ + t];
    int f32 = *flag;
    Ebf[(size_t)r * EMB + threadIdx.x] = f2bf(ldin(table, (size_t)idx * EMB + threadIdx.x, f32));
}

// ---------------------------------------------------------------------------
// bf16 MFMA GEMM: C[M,N] = A[M,K]·B[N,K]^T (+bias0+bias1+addA+addB)
// 64x64 tile, BK=32, 4 waves (2x2 16x16x32 mfma each). A/B/biases are
// canonical bf16. If dflag!=null the epilogue writes Cf (f32) when *dflag
// else Cbf (bf16) — used to write raw logits into d_out per output dtype.
// ---------------------------------------------------------------------------
__global__ __launch_bounds__(256) void gemm_bt(const u16* __restrict__ A, int lda,
                                               const u16* __restrict__ Bm, int ldb,
                                               int M, int N, int K,
                                               const u16* __restrict__ bias0,
                                               const u16* __restrict__ bias1,
                                               const float* __restrict__ addA,
                                               const u16* __restrict__ addB,
                                               float* __restrict__ Cf,
                                               u16* __restrict__ Cbf, int ldc,
                                               const int* __restrict__ dflag) {
    __shared__ u16 As[64 * 32];
    __shared__ u16 Bs[64 * 32];
    int tid = threadIdx.x;
    int n0 = blockIdx.x * 64, m0 = blockIdx.y * 64;
    int outmode = dflag ? *dflag : -1;
    int w = tid >> 6, lane = tid & 63;
    int wm = (w & 1) * 32, wn = (w >> 1) * 32;
    int mrow = lane & 15, quad = lane >> 4;
    float4v acc[2][2] = {};
    int lr = tid >> 2;
    int lc = (tid & 3) * 8;
    for (int k0 = 0; k0 < K; k0 += 32) {
        *(uint4*)(&As[lr * 32 + lc]) = *(const uint4*)(A + (size_t)(m0 + lr) * lda + k0 + lc);
        int nrow = n0 + lr;
        uint4 bv_ = make_uint4(0u, 0u, 0u, 0u);
        if (nrow < N) bv_ = *(const uint4*)(Bm + (size_t)nrow * ldb + k0 + lc);
        *(uint4*)(&Bs[lr * 32 + lc]) = bv_;
        __syncthreads();
        short8 afrag[2], bfrag[2];
        #pragma unroll
        for (int i = 0; i < 2; i++)
            afrag[i] = *(const short8*)(&As[(wm + i * 16 + mrow) * 32 + quad * 8]);
        #pragma unroll
        for (int j = 0; j < 2; j++)
            bfrag[j] = *(const short8*)(&Bs[(wn + j * 16 + mrow) * 32 + quad * 8]);
        #pragma unroll
        for (int i = 0; i < 2; i++)
            #pragma unroll
            for (int j = 0; j < 2; j++)
                acc[i][j] = __builtin_amdgcn_mfma_f32_16x16x32_bf16(afrag[i], bfrag[j], acc[i][j], 0, 0, 0);
        __syncthreads();
    }
    #pragma unroll
    for (int i = 0; i < 2; i++) {
        #pragma unroll
        for (int j = 0; j < 2; j++) {
            #pragma unroll
            for (int r = 0; r < 4; r++) {
                int grow = m0 + wm + i * 16 + quad * 4 + r;
                int gcol = n0 + wn + j * 16 + mrow;
                if (gcol < N) {
                    float v = acc[i][j][r];
                    if (bias0) v += bf2f(bias0[gcol]);
                    if (bias1) v += bf2f(bias1[gcol]);
                    size_t off = (size_t)grow * ldc + gcol;
                    if (addA) v += addA[off];
                    if (addB) v += bf2f(addB[off]);
                    if (outmode < 0) {
                        if (Cf) Cf[off] = v;
                        if (Cbf) Cbf[off] = f2bf(v);
                    } else if (outmode) {
                        Cf[off] = v;
                    } else {
                        Cbf[off] = f2bf(v);
                    }
                }
            }
        }
    }
}

// LSTM elementwise: gates [128,2048] f32 -> c (f32), h (bf16), h_all[t] (bf16)
__global__ __launch_bounds__(256) void lstm_step(const float* __restrict__ gates,
                                                 float* __restrict__ c,
                                                 u16* __restrict__ h_bf,
                                                 u16* __restrict__ h_all, int t) {
    int idx = blockIdx.x * 256 + threadIdx.x;  // 0..65535
    int b = idx >> 9, k = idx & 511;
    const float* g = gates + (size_t)b * 2048;
    float ig = sigmoidf_(g[k]);
    float fg = sigmoidf_(g[512 + k]);
    float gg = tanhf(g[1024 + k]);
    float og = sigmoidf_(g[1536 + k]);
    float cn = fg * c[idx] + ig * gg;
    c[idx] = cn;
    float h = og * tanhf(cn);
    u16 hb = f2bf(h);
    h_bf[idx] = hb;
    h_all[((size_t)t * B_ + b) * HID + k] = hb;
}

// ---------------------------------------------------------------------------
// fused log_softmax + softmax in place over d_out. Raw logits sit in the
// second half (softmax region) of d_out, in the output dtype per *flag.
// ---------------------------------------------------------------------------
__global__ __launch_bounds__(256) void softmax_out(void* __restrict__ outv,
                                                   const int* __restrict__ flag) {
    __shared__ float red[256];
    int r = blockIdx.x, tid = threadIdx.x;
    int f32 = *flag;
    float* outf = (float*)outv;
    u16* outb = (u16*)outv;
    size_t half = (size_t)T_ * B_ * VOC;
    float lv[40];
    float m = -1e30f;
    #pragma unroll
    for (int j = 0; j < 40; j++) {
        int i = tid + j * 256;
        float v = -1e30f;
        if (i < VOC) {
            size_t p = half + (size_t)r * VOC + i;
            v = f32 ? outf[p] : bf2f(outb[p]);
        }
        lv[j] = v;
        m = fmaxf(m, v);
    }
    red[tid] = m; __syncthreads();
    for (int s = 128; s; s >>= 1) { if (tid < s) red[tid] = fmaxf(red[tid], red[tid + s]); __syncthreads(); }
    m = red[0]; __syncthreads();
    float sum = 0.f;
    #pragma unroll
    for (int j = 0; j < 40; j++) sum += expf(lv[j] - m);
    red[tid] = sum; __syncthreads();
    for (int s = 128; s; s >>= 1) { if (tid < s) red[tid] += red[tid + s]; __syncthreads(); }
    float logZ = m + logf(red[0]);
    #pragma unroll
    for (int j = 0; j < 40; j++) {
        int i = tid + j * 256;
        if (i < VOC) {
            float v = lv[j] - logZ;
            size_t pl = (size_t)r * VOC + i;
            size_t ps = half + pl;
            float sm = expf(v);
            if (f32) { outf[pl] = v; outf[ps] = sm; }
            else { outb[pl] = f2bf(v); outb[ps] = f2bf(sm); }
        }
    }
}

extern "C" void kernel_launch(void* const* d_in, const int* in_sizes, int n_in,
                              void* d_out, int out_size, void* d_ws, size_t ws_size,
                              hipStream_t stream) {
    const void* features = d_in[0];
    const int* captions = (const int*)d_in[1];
    // d_in[5] bv, d_in[6] Wa, d_in[7] ba: unused (softmax shift-invariance)
    const void* Wv = d_in[4];
    const void* embed_t = d_in[8];

    // workspace layout (~33.7 MB)
    char* base = (char*)d_ws;
    int*   flag     = (int*)(base + 0);                 // 1024
    u16*   fbar_bf  = (u16*)(base + 1024);              // 131072
    u16*   ctx_bf   = (u16*)(base + 132096);            // 131072
    u16*   h_bf     = (u16*)(base + 263168);            // 131072
    float* c_f32    = (float*)(base + 394240);          // 262144
    float* gconst   = (float*)(base + 656384);          // 1048576
    u16*   Ebf      = (u16*)(base + 1704960);           // 1310720
    u16*   Eproj    = (u16*)(base + 3015680);           // 10485760
    float* gates    = (float*)(base + 13501440);        // 1048576
    u16*   h_all    = (u16*)(base + 14550016);          // 2621440
    u16*   cWih_    = (u16*)(base + 17171456);          // canonical bf16 weights:
    u16*   cWhh_    = (u16*)(base + 20317184);          // offsets below
    u16*   cWo_     = (u16*)(base + 22414336);
    u16*   cWinh_   = (u16*)(base + 32654336);
    u16*   cWinc_   = (u16*)(base + 33178624);
    u16*   cbih_    = (u16*)(base + 33702912);
    u16*   cbhh_    = (u16*)(base + 33707008);
    u16*   cbo_     = (u16*)(base + 33711104);          // ends 33731104

    // 0) detect input dtype (f32 vs bf16) from features' bit patterns
    detect_dtype<<<1, 256, 0, stream>>>((const u16*)features, flag);
    // canonicalize weights to bf16
    conv_bf<<<(in_sizes[9]  + 255) / 256, 256, 0, stream>>>(d_in[9],  cWih_,  in_sizes[9],  flag);
    conv_bf<<<(in_sizes[10] + 255) / 256, 256, 0, stream>>>(d_in[10], cWhh_,  in_sizes[10], flag);
    conv_bf<<<(in_sizes[13] + 255) / 256, 256, 0, stream>>>(d_in[13], cWo_,   in_sizes[13], flag);
    conv_bf<<<(in_sizes[2]  + 255) / 256, 256, 0, stream>>>(d_in[2],  cWinh_, in_sizes[2],  flag);
    conv_bf<<<(in_sizes[3]  + 255) / 256, 256, 0, stream>>>(d_in[3],  cWinc_, in_sizes[3],  flag);
    conv_bf<<<(in_sizes[11] + 255) / 256, 256, 0, stream>>>(d_in[11], cbih_,  in_sizes[11], flag);
    conv_bf<<<(in_sizes[12] + 255) / 256, 256, 0, stream>>>(d_in[12], cbhh_,  in_sizes[12], flag);
    conv_bf<<<(in_sizes[14] + 255) / 256, 256, 0, stream>>>(d_in[14], cbo_,   in_sizes[14], flag);

    // 1) feature reductions (flag-aware reads)
    prep_kernel<<<B_, 256, 0, stream>>>(features, Wv, flag, fbar_bf, ctx_bf);
    // 2) embedding gather (time-major, flag-aware)
    gather_emb<<<T_ * B_, 256, 0, stream>>>(captions, embed_t, flag, Ebf);
    // 3) h0 = fbar @ W_init_h^T (bf16), c0 = fbar @ W_init_c^T (f32)
    gemm_bt<<<dim3(512 / 64, B_ / 64), 256, 0, stream>>>(
        fbar_bf, 512, cWinh_, 512, B_, 512, 512,
        nullptr, nullptr, nullptr, nullptr, nullptr, h_bf, 512, nullptr);
    gemm_bt<<<dim3(512 / 64, B_ / 64), 256, 0, stream>>>(
        fbar_bf, 512, cWinc_, 512, B_, 512, 512,
        nullptr, nullptr, nullptr, nullptr, c_f32, nullptr, 512, nullptr);
    // 4) gates_const = ctx @ W_ih[:, :512]^T + b_ih + b_hh
    gemm_bt<<<dim3(2048 / 64, B_ / 64), 256, 0, stream>>>(
        ctx_bf, 512, cWih_, 768, B_, 2048, 512,
        cbih_, cbhh_, nullptr, nullptr, gconst, nullptr, 2048, nullptr);
    // 5) Eproj = E @ W_ih[:, 512:768]^T   [2560, 2048] bf16
    gemm_bt<<<dim3(2048 / 64, (T_ * B_) / 64), 256, 0, stream>>>(
        Ebf, 256, cWih_ + 512, 768, T_ * B_, 2048, 256,
        nullptr, nullptr, nullptr, nullptr, nullptr, Eproj, 2048, nullptr);
    // 6) recurrence
    for (int t = 0; t < T_; t++) {
        gemm_bt<<<dim3(2048 / 64, B_ / 64), 256, 0, stream>>>(
            h_bf, 512, cWhh_, 512, B_, 2048, 512,
            nullptr, nullptr, gconst, Eproj + (size_t)t * B_ * 2048, gates, nullptr, 2048, nullptr);
        lstm_step<<<(B_ * HID) / 256, 256, 0, stream>>>(gates, c_f32, h_bf, h_all, t);
    }
    // 7) logits = h_all @ Wo^T + bo -> raw logits into d_out's second half,
    //    written in the output dtype selected by *flag
    size_t half = (size_t)T_ * B_ * VOC;
    gemm_bt<<<dim3((VOC + 63) / 64, (T_ * B_) / 64), 256, 0, stream>>>(
        h_all, 512, cWo_, 512, T_ * B_, VOC, 512,
        cbo_, nullptr, nullptr, nullptr, (float*)d_out + half, (u16*)d_out + half, VOC, flag);
    // 8) fused log_softmax + softmax in place on d_out
    softmax_out<<<T_ * B_, 256, 0, stream>>>(d_out, flag);
}

// Round 4
// 778.858 us; speedup vs baseline: 1.1784x; 1.1784x over previous
//
#include <hip/hip_runtime.h>

typedef unsigned short u16;
typedef unsigned int u32;

typedef __attribute__((ext_vector_type(8))) short short8;
typedef __attribute__((ext_vector_type(4))) float float4v;

__device__ __forceinline__ float bf2f(u16 u) { return __uint_as_float(((u32)u) << 16); }
__device__ __forceinline__ u16 f2bf(float f) {
    u32 x = __float_as_uint(f);
    return (u16)((x + 0x7fffu + ((x >> 16) & 1u)) >> 16);
}
__device__ __forceinline__ float sigmoidf_(float x) { return 1.0f / (1.0f + expf(-x)); }

#define B_ 128
#define T_ 20
#define VISN 196
#define VISD 512
#define EMB 256
#define HID 512
#define VOC 10000
#define VOCP 10112   /* padded to 79*128 */
#define NBLK 64      /* recurrence grid */

// ---------------------------------------------------------------------------
// fused weight conversion f32 -> bf16 (+ zero-pad Wo/bo to VOCP, zero barrier)
// one element per thread; segments by flat gid.
// ---------------------------------------------------------------------------
__global__ __launch_bounds__(256) void conv_all(
    const float* __restrict__ Wih, const float* __restrict__ Whh,
    const float* __restrict__ Wo,  const float* __restrict__ Winh,
    const float* __restrict__ Winc, const float* __restrict__ bih,
    const float* __restrict__ bhh, const float* __restrict__ bo,
    u16* __restrict__ cWih, u16* __restrict__ cWhh, u16* __restrict__ cWo,
    u16* __restrict__ cWinit, u16* __restrict__ cbih, u16* __restrict__ cbhh,
    u16* __restrict__ cbo, int* __restrict__ barcnt) {
    const int e0 = 1572864, e1 = 2621440, e2 = 7798784, e3 = 8060928,
              e4 = 8323072, e5 = 8325120, e6 = 8327168, e7 = 8337280;
    int gid = blockIdx.x * 256 + threadIdx.x;
    if (gid == 0) *barcnt = 0;
    if (gid >= e7) return;
    if (gid < e0) { cWih[gid] = f2bf(Wih[gid]); }
    else if (gid < e1) { int l = gid - e0; cWhh[l] = f2bf(Whh[l]); }
    else if (gid < e2) {
        int l = gid - e1; int row = l >> 9, col = l & 511;
        cWo[l] = (row < VOC) ? f2bf(Wo[(size_t)row * 512 + col]) : (u16)0;
    }
    else if (gid < e3) { int l = gid - e2; cWinit[l] = f2bf(Winh[l]); }
    else if (gid < e4) { int l = gid - e3; cWinit[262144 + l] = f2bf(Winc[l]); }
    else if (gid < e5) { int l = gid - e4; cbih[l] = f2bf(bih[l]); }
    else if (gid < e6) { int l = gid - e5; cbhh[l] = f2bf(bhh[l]); }
    else { int l = gid - e6; cbo[l] = (l < VOC) ? f2bf(bo[l]) : (u16)0; }
}

// ---------------------------------------------------------------------------
// att: alpha[b,n] = softmax_n(features[b,n,:]·Wv). h-term of the logit is
// constant over n -> softmax-invariant -> dropped. One block per b.
// ---------------------------------------------------------------------------
__global__ __launch_bounds__(256) void att_kernel(const float* __restrict__ feat,
                                                  const float* __restrict__ Wv,
                                                  float* __restrict__ alpha) {
    __shared__ float wv[512];
    __shared__ float att[VISN];
    __shared__ float red[256];
    int b = blockIdx.x, tid = threadIdx.x;
    wv[tid] = Wv[tid];
    wv[tid + 256] = Wv[tid + 256];
    __syncthreads();
    int w = tid >> 6, lane = tid & 63;
    for (int n = w; n < VISN; n += 4) {
        const float4* fp = (const float4*)(feat + ((size_t)b * VISN + n) * VISD) + lane * 2;
        float4 a = fp[0], c = fp[1];
        const float* wp = wv + lane * 8;
        float s = a.x * wp[0] + a.y * wp[1] + a.z * wp[2] + a.w * wp[3]
                + c.x * wp[4] + c.y * wp[5] + c.z * wp[6] + c.w * wp[7];
        #pragma unroll
        for (int off = 32; off; off >>= 1) s += __shfl_down(s, off);
        if (lane == 0) att[n] = s;
    }
    __syncthreads();
    float m = -1e30f;
    for (int i = tid; i < VISN; i += 256) m = fmaxf(m, att[i]);
    red[tid] = m; __syncthreads();
    for (int s = 128; s; s >>= 1) { if (tid < s) red[tid] = fmaxf(red[tid], red[tid + s]); __syncthreads(); }
    m = red[0]; __syncthreads();
    float sum = 0.f;
    for (int i = tid; i < VISN; i += 256) { float e = expf(att[i] - m); att[i] = e; sum += e; }
    red[tid] = sum; __syncthreads();
    for (int s = 128; s; s >>= 1) { if (tid < s) red[tid] += red[tid + s]; __syncthreads(); }
    float inv = 1.0f / red[0]; __syncthreads();
    for (int i = tid; i < VISN; i += 256) alpha[b * VISN + i] = att[i] * inv;
}

// ---------------------------------------------------------------------------
// ctx/fbar: fbar = mean_n feat, ctx = sum_n alpha*feat. grid (2 vslices, 128 b)
// ---------------------------------------------------------------------------
__global__ __launch_bounds__(256) void ctx_fbar(const float* __restrict__ feat,
                                                const float* __restrict__ alpha,
                                                u16* __restrict__ fbar_bf,
                                                u16* __restrict__ ctx_bf) {
    __shared__ float al[VISN];
    int b = blockIdx.y, tid = threadIdx.x;
    int v = blockIdx.x * 256 + tid;
    if (tid < VISN) al[tid] = alpha[b * VISN + tid];
    __syncthreads();
    float accf = 0.f, accc = 0.f;
    const float* fp = feat + (size_t)b * VISN * VISD + v;
    #pragma unroll 4
    for (int n = 0; n < VISN; n++) {
        float f = fp[(size_t)n * VISD];
        accf += f;
        accc += al[n] * f;
    }
    fbar_bf[b * VISD + v] = f2bf(accf / (float)VISN);
    ctx_bf[b * VISD + v] = f2bf(accc);
}

// gather embeddings, time-major r = t*B + b
__global__ void gather_emb(const int* __restrict__ captions, const float* __restrict__ table,
                           u16* __restrict__ Ebf) {
    int r = blockIdx.x;
    int t = r >> 7, b = r & 127;
    int idx = captions[b * T_ + t];
    Ebf[(size_t)r * EMB + threadIdx.x] = f2bf(table[(size_t)idx * EMB + threadIdx.x]);
}

// ---------------------------------------------------------------------------
// bf16 MFMA GEMM, 64x64 tile, BK=32. C = A[M,K]·B[N,K]^T + biases + addA.
// mode 0: write bf16 Cbf; mode 1: write f32 Cf; mode 2: h0c0 split
// (col<512 -> Cbf=h bf16 at grow*512+col, else Cf=c f32 at grow*512+col-512).
// addA (f32) indexed [(grow & rowmask)*ldc + gcol].
// ---------------------------------------------------------------------------
__global__ __launch_bounds__(256) void gemm_bt(const u16* __restrict__ A, int lda,
                                               const u16* __restrict__ Bm, int ldb,
                                               int M, int N, int K,
                                               const u16* __restrict__ bias0,
                                               const u16* __restrict__ bias1,
                                               const float* __restrict__ addA, int rowmask,
                                               float* __restrict__ Cf,
                                               u16* __restrict__ Cbf, int ldc, int mode) {
    __shared__ u16 As[64 * 32];
    __shared__ u16 Bs[64 * 32];
    int tid = threadIdx.x;
    int n0 = blockIdx.x * 64, m0 = blockIdx.y * 64;
    int w = tid >> 6, lane = tid & 63;
    int wm = (w & 1) * 32, wn = (w >> 1) * 32;
    int mrow = lane & 15, quad = lane >> 4;
    float4v acc[2][2] = {};
    int lr = tid >> 2;
    int lc = (tid & 3) * 8;
    for (int k0 = 0; k0 < K; k0 += 32) {
        *(uint4*)(&As[lr * 32 + lc]) = *(const uint4*)(A + (size_t)(m0 + lr) * lda + k0 + lc);
        *(uint4*)(&Bs[lr * 32 + lc]) = *(const uint4*)(Bm + (size_t)(n0 + lr) * ldb + k0 + lc);
        __syncthreads();
        short8 afrag[2], bfrag[2];
        #pragma unroll
        for (int i = 0; i < 2; i++)
            afrag[i] = *(const short8*)(&As[(wm + i * 16 + mrow) * 32 + quad * 8]);
        #pragma unroll
        for (int j = 0; j < 2; j++)
            bfrag[j] = *(const short8*)(&Bs[(wn + j * 16 + mrow) * 32 + quad * 8]);
        #pragma unroll
        for (int i = 0; i < 2; i++)
            #pragma unroll
            for (int j = 0; j < 2; j++)
                acc[i][j] = __builtin_amdgcn_mfma_f32_16x16x32_bf16(afrag[i], bfrag[j], acc[i][j], 0, 0, 0);
        __syncthreads();
    }
    #pragma unroll
    for (int i = 0; i < 2; i++) {
        #pragma unroll
        for (int j = 0; j < 2; j++) {
            #pragma unroll
            for (int r = 0; r < 4; r++) {
                int grow = m0 + wm + i * 16 + quad * 4 + r;
                int gcol = n0 + wn + j * 16 + mrow;
                float v = acc[i][j][r];
                if (bias0) v += bf2f(bias0[gcol]);
                if (bias1) v += bf2f(bias1[gcol]);
                if (addA) v += addA[(size_t)(grow & rowmask) * ldc + gcol];
                if (mode == 0) {
                    Cbf[(size_t)grow * ldc + gcol] = f2bf(v);
                } else if (mode == 1) {
                    Cf[(size_t)grow * ldc + gcol] = v;
                } else {  // mode 2: h0/c0 split
                    if (gcol < 512) Cbf[(size_t)grow * 512 + gcol] = f2bf(v);
                    else Cf[(size_t)grow * 512 + gcol - 512] = v;
                }
            }
        }
    }
}

// ---------------------------------------------------------------------------
// persistent fused recurrence. 64 blocks; block j owns gate k-slice [8j,8j+8)
// of all 4 gate groups (32 gate cols), so LSTM elementwise is block-local.
// W_hh slice LDS-resident; c-state in registers; h ping-pong in global with
// one device-scope grid barrier per step.
// ---------------------------------------------------------------------------
__global__ __launch_bounds__(256) void recurrence(
    const u16* __restrict__ Whh,      // [2048,512] bf16
    const float* __restrict__ gbase,  // [2560,2048] f32 (row = t*128+b)
    const float* __restrict__ c0,     // [128,512] f32
    u16* __restrict__ h_pp,           // [2][128*512] bf16, buf0 = h0
    u16* __restrict__ h_all,          // [2560,512] bf16
    int* __restrict__ barcnt) {
    __shared__ u16 Ws[32 * 520];      // padded stride (bank spread)
    __shared__ u16 As[128 * 40];      // h staging, padded
    __shared__ float Gt[128 * 33];    // gates, padded
    int j = blockIdx.x, tid = threadIdx.x;
    // load W_hh slice: local col c -> global row (c>>3)*512 + 8j + (c&7)
    for (int idx = tid; idx < 32 * 64; idx += 256) {
        int c = idx >> 6, q = idx & 63;
        int grow = ((c >> 3) << 9) + 8 * j + (c & 7);
        *(uint4*)&Ws[c * 520 + q * 8] = *(const uint4*)&Whh[(size_t)grow * 512 + q * 8];
    }
    // c-state: thread owns pairs p = tid*4 + q, p = b*8 + kc
    float cst[4];
    int pb = (tid * 4) >> 3, pk = (tid * 4) & 7;  // 4 consecutive kc, same b
    #pragma unroll
    for (int q = 0; q < 4; q++) cst[q] = c0[pb * 512 + 8 * j + pk + q];
    __syncthreads();
    int w = tid >> 6, lane = tid & 63;
    int mrow = lane & 15, quad = lane >> 4;
    for (int t = 0; t < T_; t++) {
        const u16* hcur = h_pp + (t & 1) * (B_ * HID);
        u16* hnxt = (u16*)h_pp + ((t + 1) & 1) * (B_ * HID);
        float4v acc[2][2] = {};
        for (int k0 = 0; k0 < 512; k0 += 32) {
            #pragma unroll
            for (int q = 0; q < 2; q++) {
                int idx = tid * 2 + q;          // 0..511 uint4s
                int r = idx >> 2, cc = (idx & 3) * 8;
                *(uint4*)&As[r * 40 + cc] = *(const uint4*)&hcur[(size_t)r * 512 + k0 + cc];
            }
            __syncthreads();
            short8 af[2], bfv[2];
            #pragma unroll
            for (int i = 0; i < 2; i++)
                af[i] = *(const short8*)&As[(32 * w + i * 16 + mrow) * 40 + quad * 8];
            #pragma unroll
            for (int n2 = 0; n2 < 2; n2++)
                bfv[n2] = *(const short8*)&Ws[(n2 * 16 + mrow) * 520 + k0 + quad * 8];
            #pragma unroll
            for (int i = 0; i < 2; i++)
                #pragma unroll
                for (int n2 = 0; n2 < 2; n2++)
                    acc[i][n2] = __builtin_amdgcn_mfma_f32_16x16x32_bf16(af[i], bfv[n2], acc[i][n2], 0, 0, 0);
            __syncthreads();
        }
        // epilogue: add gbase, deposit to Gt
        #pragma unroll
        for (int i = 0; i < 2; i++) {
            #pragma unroll
            for (int n2 = 0; n2 < 2; n2++) {
                int lcol = n2 * 16 + mrow;
                int G = ((lcol >> 3) << 9) + 8 * j + (lcol & 7);
                #pragma unroll
                for (int r = 0; r < 4; r++) {
                    int grow = 32 * w + i * 16 + quad * 4 + r;
                    Gt[grow * 33 + lcol] = acc[i][n2][r] +
                        gbase[(size_t)(t * B_ + grow) * 2048 + G];
                }
            }
        }
        __syncthreads();
        // LSTM elementwise on owned slice
        {
            u16 hb[4];
            #pragma unroll
            for (int q = 0; q < 4; q++) {
                int kc = pk + q;
                float ig = sigmoidf_(Gt[pb * 33 + kc]);
                float fg = sigmoidf_(Gt[pb * 33 + 8 + kc]);
                float gg = tanhf(Gt[pb * 33 + 16 + kc]);
                float og = sigmoidf_(Gt[pb * 33 + 24 + kc]);
                float cn = fg * cst[q] + ig * gg;
                cst[q] = cn;
                hb[q] = f2bf(og * tanhf(cn));
            }
            size_t off = (size_t)pb * 512 + 8 * j + pk;
            *(ushort4*)&hnxt[off] = *(ushort4*)hb;
            *(ushort4*)&h_all[(size_t)(t * B_ + pb) * 512 + 8 * j + pk] = *(ushort4*)hb;
        }
        __syncthreads();
        // grid barrier: release h writes, wait for all blocks at step t
        if (tid == 0) {
            __threadfence();
            atomicAdd(barcnt, 1);
            int target = NBLK * (t + 1);
            while (__hip_atomic_load(barcnt, __ATOMIC_ACQUIRE, __HIP_MEMORY_SCOPE_AGENT) < target)
                __builtin_amdgcn_s_sleep(2);
            __threadfence();
        }
        __syncthreads();
    }
}

// ---------------------------------------------------------------------------
// logits GEMM, 128x128 tile, BK=32, 4 waves each 64x64 (4x4 of 16x16x32).
// A = h_all [2560,512], B = cWo [VOCP,512] (zero-padded). C f32 -> d_out
// second half, col-guarded, + bo.
// ---------------------------------------------------------------------------
__global__ __launch_bounds__(256) void gemm128(const u16* __restrict__ A,
                                               const u16* __restrict__ Bm,
                                               const u16* __restrict__ biasbf,
                                               float* __restrict__ C) {
    __shared__ u16 As[128 * 32];
    __shared__ u16 Bs[128 * 32];
    int tid = threadIdx.x;
    int n0 = blockIdx.x * 128, m0 = blockIdx.y * 128;
    int w = tid >> 6, lane = tid & 63;
    int wm = (w & 1) * 64, wn = (w >> 1) * 64;
    int mrow = lane & 15, quad = lane >> 4;
    float4v acc[4][4] = {};
    for (int k0 = 0; k0 < 512; k0 += 32) {
        #pragma unroll
        for (int q = 0; q < 2; q++) {
            int idx = tid * 2 + q;              // 0..511 uint4s per matrix
            int r = idx >> 2, cc = (idx & 3) * 8;
            *(uint4*)&As[r * 32 + cc] = *(const uint4*)&A[(size_t)(m0 + r) * 512 + k0 + cc];
            *(uint4*)&Bs[r * 32 + cc] = *(const uint4*)&Bm[(size_t)(n0 + r) * 512 + k0 + cc];
        }
        __syncthreads();
        short8 af[4], bfv[4];
        #pragma unroll
        for (int i = 0; i < 4; i++)
            af[i] = *(const short8*)&As[(wm + i * 16 + mrow) * 32 + quad * 8];
        #pragma unroll
        for (int jn = 0; jn < 4; jn++)
            bfv[jn] = *(const short8*)&Bs[(wn + jn * 16 + mrow) * 32 + quad * 8];
        #pragma unroll
        for (int i = 0; i < 4; i++)
            #pragma unroll
            for (int jn = 0; jn < 4; jn++)
                acc[i][jn] = __builtin_amdgcn_mfma_f32_16x16x32_bf16(af[i], bfv[jn], acc[i][jn], 0, 0, 0);
        __syncthreads();
    }
    #pragma unroll
    for (int i = 0; i < 4; i++) {
        #pragma unroll
        for (int jn = 0; jn < 4; jn++) {
            int gcol = n0 + wn + jn * 16 + mrow;
            if (gcol >= VOC) continue;
            float bias = bf2f(biasbf[gcol]);
            #pragma unroll
            for (int r = 0; r < 4; r++) {
                int grow = m0 + wm + i * 16 + quad * 4 + r;
                C[(size_t)grow * VOC + gcol] = acc[i][jn][r] + bias;
            }
        }
    }
}

// ---------------------------------------------------------------------------
// fused log_softmax + softmax over d_out rows (f32). Raw logits in 2nd half.
// ---------------------------------------------------------------------------
__global__ __launch_bounds__(256) void softmax_out(float* __restrict__ out) {
    __shared__ float red[256];
    int r = blockIdx.x, tid = threadIdx.x;
    const size_t HALF4 = (size_t)T_ * B_ * VOC / 4;  // in float4 units
    float4* outv = (float4*)out;
    float4* src = outv + HALF4 + (size_t)r * (VOC / 4);
    float4 lv[10];
    float m = -1e30f;
    #pragma unroll
    for (int jq = 0; jq < 10; jq++) {
        int i4 = tid + jq * 256;
        if (i4 < VOC / 4) {
            float4 v = src[i4];
            lv[jq] = v;
            m = fmaxf(m, fmaxf(fmaxf(v.x, v.y), fmaxf(v.z, v.w)));
        } else {
            lv[jq] = make_float4(-1e30f, -1e30f, -1e30f, -1e30f);
        }
    }
    red[tid] = m; __syncthreads();
    for (int s = 128; s; s >>= 1) { if (tid < s) red[tid] = fmaxf(red[tid], red[tid + s]); __syncthreads(); }
    m = red[0]; __syncthreads();
    float sum = 0.f;
    #pragma unroll
    for (int jq = 0; jq < 10; jq++)
        sum += expf(lv[jq].x - m) + expf(lv[jq].y - m) + expf(lv[jq].z - m) + expf(lv[jq].w - m);
    red[tid] = sum; __syncthreads();
    for (int s = 128; s; s >>= 1) { if (tid < s) red[tid] += red[tid + s]; __syncthreads(); }
    float logZ = m + logf(red[0]);
    float4* dls = outv + (size_t)r * (VOC / 4);
    #pragma unroll
    for (int jq = 0; jq < 10; jq++) {
        int i4 = tid + jq * 256;
        if (i4 < VOC / 4) {
            float4 v = lv[jq];
            float4 ls = make_float4(v.x - logZ, v.y - logZ, v.z - logZ, v.w - logZ);
            dls[i4] = ls;
            src[i4] = make_float4(expf(ls.x), expf(ls.y), expf(ls.z), expf(ls.w));
        }
    }
}

extern "C" void kernel_launch(void* const* d_in, const int* in_sizes, int n_in,
                              void* d_out, int out_size, void* d_ws, size_t ws_size,
                              hipStream_t stream) {
    const float* features = (const float*)d_in[0];
    const int* captions   = (const int*)d_in[1];
    const float* W_init_h = (const float*)d_in[2];
    const float* W_init_c = (const float*)d_in[3];
    const float* Wv       = (const float*)d_in[4];
    // d_in[5] bv, d_in[6] Wa, d_in[7] ba unused (softmax shift-invariance)
    const float* embed_t  = (const float*)d_in[8];
    const float* W_ih     = (const float*)d_in[9];
    const float* W_hh     = (const float*)d_in[10];
    const float* b_ih     = (const float*)d_in[11];
    const float* b_hh     = (const float*)d_in[12];
    const float* Wo       = (const float*)d_in[13];
    const float* bo       = (const float*)d_in[14];
    float* out = (float*)d_out;

    // workspace layout (~43.5 MB)
    char* base = (char*)d_ws;
    int*   barcnt  = (int*)(base + 0);
    float* alpha   = (float*)(base + 1024);
    u16*   fbar_bf = (u16*)(base + 103424);
    u16*   ctx_bf  = (u16*)(base + 234496);
    u16*   h_pp    = (u16*)(base + 365568);       // 2 x 128*512 bf16
    float* c_f32   = (float*)(base + 627712);
    float* gconst  = (float*)(base + 889856);     // [128,2048] f32
    u16*   Ebf     = (u16*)(base + 1938432);      // [2560,256] bf16
    float* gbase   = (float*)(base + 3249152);    // [2560,2048] f32
    u16*   h_all   = (u16*)(base + 24220672);     // [2560,512] bf16
    u16*   cWih    = (u16*)(base + 26842112);     // [2048,768] bf16
    u16*   cWhh    = (u16*)(base + 29987840);     // [2048,512]
    u16*   cWo     = (u16*)(base + 32084992);     // [VOCP,512] padded
    u16*   cWinit  = (u16*)(base + 42439680);     // [1024,512] (Winh;Winc)
    u16*   cbih    = (u16*)(base + 43488256);
    u16*   cbhh    = (u16*)(base + 43492352);
    u16*   cbo     = (u16*)(base + 43496448);     // [VOCP] padded

    // 1) weight conversion (+ barrier zero)
    conv_all<<<32568, 256, 0, stream>>>(W_ih, W_hh, Wo, W_init_h, W_init_c,
                                        b_ih, b_hh, bo,
                                        cWih, cWhh, cWo, cWinit, cbih, cbhh, cbo, barcnt);
    // 2) attention weights + context/mean features
    att_kernel<<<B_, 256, 0, stream>>>(features, Wv, alpha);
    ctx_fbar<<<dim3(2, B_), 256, 0, stream>>>(features, alpha, fbar_bf, ctx_bf);
    // 3) embeddings (time-major)
    gather_emb<<<T_ * B_, 256, 0, stream>>>(captions, embed_t, Ebf);
    // 4) h0 | c0 = fbar @ [Winh; Winc]^T   (split epilogue)
    gemm_bt<<<dim3(16, 2), 256, 0, stream>>>(
        fbar_bf, 512, cWinit, 512, B_, 1024, 512,
        nullptr, nullptr, nullptr, -1, c_f32, h_pp, 1024, 2);
    // 5) gconst = ctx @ W_ih[:, :512]^T + b_ih + b_hh   [128,2048] f32
    gemm_bt<<<dim3(32, 2), 256, 0, stream>>>(
        ctx_bf, 512, cWih, 768, B_, 2048, 512,
        cbih, cbhh, nullptr, -1, gconst, nullptr, 2048, 1);
    // 6) gbase = E @ W_ih[:, 512:768]^T + gconst[b]   [2560,2048] f32
    gemm_bt<<<dim3(32, 40), 256, 0, stream>>>(
        Ebf, 256, cWih + 512, 768, T_ * B_, 2048, 256,
        nullptr, nullptr, gconst, 127, gbase, nullptr, 2048, 1);
    // 7) fused 20-step LSTM recurrence (single persistent launch)
    recurrence<<<NBLK, 256, 0, stream>>>(cWhh, gbase, c_f32, h_pp, h_all, barcnt);
    // 8) logits = h_all @ Wo^T + bo -> f32 raw into d_out's second half
    gemm128<<<dim3(VOCP / 128, (T_ * B_) / 128), 256, 0, stream>>>(
        h_all, cWo, cbo, out + (size_t)T_ * B_ * VOC);
    // 9) fused log_softmax + softmax in place
    softmax_out<<<T_ * B_, 256, 0, stream>>>(out);
}